// Round 3
// baseline (272.960 us; speedup 1.0000x reference)
//
#include <hip/hip_runtime.h>
#include <hip/hip_bf16.h>

typedef __attribute__((ext_vector_type(8))) short short8;
typedef __attribute__((ext_vector_type(4))) float f32x4;

#define MFMA16(a, b, c) __builtin_amdgcn_mfma_f32_16x16x32_bf16((a), (b), (c), 0, 0, 0)

// sizes: B=16, C=256, N=1024 (32x32), HEADS=4, DHEAD=64, HID=256, OTOT=768

__device__ __forceinline__ ushort f2bf(float f) {
  union { float f; unsigned u; } x; x.f = f;
  unsigned r = x.u + 0x7FFFu + ((x.u >> 16) & 1u);
  return (ushort)(r >> 16);
}

__device__ __forceinline__ float bf2f(ushort u) {
  union { unsigned u; float f; } x; x.u = ((unsigned)u) << 16;
  return x.f;
}

__device__ __forceinline__ short8 ld8(const ushort* p) {
  return *reinterpret_cast<const short8*>(p);
}

// ---------------- kernel 0a: transpose + convert x,y (b,c,n)f32 -> (b,n,c)bf16
__global__ __launch_bounds__(256) void k_tcvt(const float* __restrict__ x,
    const float* __restrict__ y, ushort* __restrict__ xbt, ushort* __restrict__ ybt) {
  int tile = blockIdx.x;
  const float* src; ushort* dst;
  if (tile >= 1024) { tile -= 1024; src = y; dst = ybt; }
  else { src = x; dst = xbt; }
  int b = tile >> 6;
  int c0 = ((tile >> 4) & 3) << 6;
  int n0 = (tile & 15) << 6;
  __shared__ ushort lds[64][65];
  int tid = threadIdx.x;
  int nl = tid & 63, cl = tid >> 6;
  const float* sb = src + ((size_t)b << 18);
#pragma unroll
  for (int s = 0; s < 16; ++s) {
    int c = cl + (s << 2);
    lds[c][nl] = f2bf(sb[(size_t)(c0 + c) * 1024 + n0 + nl]);
  }
  __syncthreads();
  ushort* db = dst + ((size_t)b << 18);
  int cl2 = tid & 63, nl2 = tid >> 6;
#pragma unroll
  for (int s = 0; s < 16; ++s) {
    int n = nl2 + (s << 2);
    db[(size_t)(n0 + n) * 256 + c0 + cl2] = lds[cl2][n];
  }
}

// ---------------- kernel 0b: convert weights to bf16 (same layout, [o][c])
__global__ __launch_bounds__(256) void k_wcvt(const float* __restrict__ wqkv,
    const float* __restrict__ wout, ushort* __restrict__ wqkvb, ushort* __restrict__ woutb) {
  const int total1 = 768 * 256;
  const int total = total1 + 256 * 256;
  for (int i = blockIdx.x * 256 + threadIdx.x; i < total; i += gridDim.x * 256) {
    if (i < total1) wqkvb[i] = f2bf(wqkv[i]);
    else woutb[i - total1] = f2bf(wout[i - total1]);
  }
}

// ---------------- kernel 1: QKV projection GEMM + partial row sum-of-squares
// flat grid 768 = 24 o-tiles x 2 n-halves x 16 b, XCD-swizzled (q=96).
// 512 thr = 8 waves; wave: 32o x 64n.
__global__ __launch_bounds__(512, 6) void k_qkv(const ushort* __restrict__ wqkvb,
    const ushort* __restrict__ xbt, const ushort* __restrict__ ybt,
    ushort* __restrict__ qraw, ushort* __restrict__ kraw,
    ushort* __restrict__ vbuf, float* __restrict__ norms2) {
  int bid = blockIdx.x;
  int lid = (bid & 7) * 96 + (bid >> 3);   // XCD swizzle: 2 b-panels per XCD
  int ox = lid % 24;
  int t = lid / 24;
  int nb = t & 1;
  int b = t >> 1;
  int o0 = ox * 32;
  const ushort* Bsrc = (o0 < 256) ? xbt : ybt;   // q from x; k,v from y
  const ushort* Bm = Bsrc + ((size_t)b << 18);
  int tid = threadIdx.x;
  int l = tid & 63, w = tid >> 6;
  int r = l & 15, g = l >> 4;
  const ushort* Ab = wqkvb + (size_t)(o0 + r) * 256 + g * 8;
  const ushort* Bb = Bm + (size_t)(nb * 512 + w * 64 + r) * 256 + g * 8;
  f32x4 acc[2][4];
#pragma unroll
  for (int i = 0; i < 2; ++i)
#pragma unroll
    for (int j = 0; j < 4; ++j) acc[i][j] = (f32x4){0.f, 0.f, 0.f, 0.f};
#pragma unroll
  for (int ks = 0; ks < 8; ++ks) {
    short8 a0 = ld8(Ab + ks * 32);
    short8 a1 = ld8(Ab + 4096 + ks * 32);
#pragma unroll
    for (int nf = 0; nf < 4; ++nf) {
      short8 bv = ld8(Bb + (size_t)nf * 4096 + ks * 32);
      acc[0][nf] = MFMA16(a0, bv, acc[0][nf]);
      acc[1][nf] = MFMA16(a1, bv, acc[1][nf]);
    }
  }
  // partial row sum-of-squares for q,k over this block's 512 n
  __shared__ float snorm[8][32];
  if (o0 < 512) {
    float ss[2][4];
#pragma unroll
    for (int mf = 0; mf < 2; ++mf)
#pragma unroll
      for (int reg = 0; reg < 4; ++reg) {
        float s = 0.f;
#pragma unroll
        for (int nf = 0; nf < 4; ++nf) { float v = acc[mf][nf][reg]; s += v * v; }
#pragma unroll
        for (int m = 1; m < 16; m <<= 1) s += __shfl_xor(s, m);
        ss[mf][reg] = s;
      }
    if (r == 0) {
#pragma unroll
      for (int mf = 0; mf < 2; ++mf)
#pragma unroll
        for (int reg = 0; reg < 4; ++reg)
          snorm[w][mf * 16 + g * 4 + reg] = ss[mf][reg];
    }
    __syncthreads();
    if (tid < 32) {
      float s = 0.f;
#pragma unroll
      for (int w2 = 0; w2 < 8; ++w2) s += snorm[w2][tid];
      norms2[(nb * 16 + b) * 512 + o0 + tid] = s;
    }
  }
  // store raw q,k and v as bf16, [b][256][1024] each
#pragma unroll
  for (int mf = 0; mf < 2; ++mf) {
    int ob = o0 + mf * 16 + g * 4;
#pragma unroll
    for (int nf = 0; nf < 4; ++nf) {
      int n = nb * 512 + w * 64 + nf * 16 + r;
#pragma unroll
      for (int reg = 0; reg < 4; ++reg) {
        ushort v = f2bf(acc[mf][nf][reg]);
        int oo = ob + reg;
        if (o0 < 256)       qraw[(((size_t)b * 256 + oo) << 10) + n] = v;
        else if (o0 < 512)  kraw[(((size_t)b * 256 + (oo - 256)) << 10) + n] = v;
        else                vbuf[(((size_t)b * 256 + (oo - 512)) << 10) + n] = v;
      }
    }
  }
}

// ---------------- kernel 1b: scale by 1/norm (SCALE folded into q) + transpose to [n][d] bf16
__global__ __launch_bounds__(256) void k_normt(const ushort* __restrict__ qraw,
    const ushort* __restrict__ kraw, const float* __restrict__ norms2,
    ushort* __restrict__ qt, ushort* __restrict__ kt) {
  int tile = blockIdx.x;
  const ushort* src; ushort* dst; int which;
  if (tile >= 1024) { tile -= 1024; src = kraw; dst = kt; which = 1; }
  else { src = qraw; dst = qt; which = 0; }
  int b = tile >> 6;
  int h = (tile >> 4) & 3;
  int n0 = (tile & 15) << 6;
  __shared__ ushort lds[64][65];
  __shared__ float fs[64];
  int tid = threadIdx.x;
  if (tid < 64) {
    int idx = b * 512 + which * 256 + h * 64 + tid;
    float ss = norms2[idx] + norms2[8192 + idx];
    fs[tid] = (which ? 1.0f : 10.0f) / fmaxf(sqrtf(ss), 1e-12f);
  }
  __syncthreads();
  const ushort* sb = src + (((size_t)b * 256 + h * 64) << 10);
  int nl = tid & 63, dl = tid >> 6;
#pragma unroll
  for (int s = 0; s < 16; ++s) {
    int d = dl + (s << 2);
    lds[d][nl] = f2bf(bf2f(sb[((size_t)d << 10) + n0 + nl]) * fs[d]);
  }
  __syncthreads();
  ushort* db = dst + (((size_t)(b * 4 + h) << 10) + n0) * 64;
  int dl2 = tid & 63, nl2 = tid >> 6;
#pragma unroll
  for (int s = 0; s < 16; ++s) {
    int n = nl2 + (s << 2);
    db[(size_t)n * 64 + dl2] = lds[dl2][n];
  }
}

// ---------------- kernel 2: fused attention (no-max softmax, unnormalized accumulate)
// flat grid 1024 = 16 i-tiles x 4 h x 16 b, XCD-swizzled (q=128) so all i-tiles
// of one (h,b) share an XCD's L2 (K/V = 256 KB, L2-resident — no LDS staging).
// 256 thr = 4 waves; wave owns 16 q-rows -> 4096 waves total, 4 blocks/CU.
__global__ __launch_bounds__(256, 4) void k_attn(const ushort* __restrict__ qt,
    const ushort* __restrict__ kt, const ushort* __restrict__ vbuf,
    ushort* __restrict__ aot) {
  int bid = blockIdx.x;
  int lid = (bid & 7) * 128 + (bid >> 3);
  int it = lid & 15;
  int hb = lid >> 4;
  int h = hb & 3;
  int b = hb >> 2;
  int tid = threadIdx.x;
  int l = tid & 63, w = tid >> 6;
  int r = l & 15, g = l >> 4;
  size_t ho = ((size_t)(b * 4 + h)) << 16;
  const ushort* Q = qt + ho;      // [n][64]
  const ushort* K = kt + ho;      // [n][64]
  const ushort* V = vbuf + ((size_t)b << 18) + ((size_t)h << 16);  // [d][n]
  int i0 = it * 64 + w * 16;
  short8 qa[2];
#pragma unroll
  for (int ks = 0; ks < 2; ++ks)
    qa[ks] = ld8(Q + (size_t)(i0 + r) * 64 + ks * 32 + g * 8);
  f32x4 oacc[4];
  float rsum[4];
#pragma unroll
  for (int j = 0; j < 4; ++j) { oacc[j] = (f32x4){0.f, 0.f, 0.f, 0.f}; rsum[j] = 0.f; }
  __shared__ __align__(16) ushort plds[4][1024];  // per-wave 16x64 bf16, XOR-swizzled
  char* plc = (char*)plds[w];
  for (int j0 = 0; j0 < 1024; j0 += 64) {
    f32x4 sacc[4];
#pragma unroll
    for (int nf = 0; nf < 4; ++nf) sacc[nf] = (f32x4){0.f, 0.f, 0.f, 0.f};
#pragma unroll
    for (int nf = 0; nf < 4; ++nf) {
      short8 k0 = ld8(K + (size_t)(j0 + nf * 16 + r) * 64 + g * 8);
      short8 k1 = ld8(K + (size_t)(j0 + nf * 16 + r) * 64 + 32 + g * 8);
      sacc[nf] = MFMA16(qa[0], k0, sacc[nf]);
      sacc[nf] = MFMA16(qa[1], k1, sacc[nf]);
    }
    // P = exp(S); accumulate row sums; write P to per-wave LDS (swizzled).
    // bf16 truncation: bias is common-mode between numerator and row sum.
#pragma unroll
    for (int nf = 0; nf < 4; ++nf)
#pragma unroll
      for (int reg = 0; reg < 4; ++reg) {
        float p = __expf(sacc[nf][reg]);
        rsum[reg] += p;
        union { float f; unsigned u; } cv; cv.f = p;
        int row = g * 4 + reg;
        int xorv = ((row ^ (row >> 3)) & 7) << 4;
        int byteo = row * 128 + (((nf * 16 + r) * 2) ^ xorv);
        *(ushort*)(plc + byteo) = (ushort)(cv.u >> 16);
      }
    // read back as A-fragments
    short8 pa[2];
#pragma unroll
    for (int ks = 0; ks < 2; ++ks) {
      int xorv = (r ^ (r >> 3)) & 7;
      int blk = (ks * 4 + g) ^ xorv;
      pa[ks] = *reinterpret_cast<const short8*>(plc + r * 128 + blk * 16);
    }
    // O += P * V^T
#pragma unroll
    for (int df = 0; df < 4; ++df) {
#pragma unroll
      for (int ks = 0; ks < 2; ++ks) {
        short8 vf = ld8(V + (size_t)(df * 16 + r) * 1024 + j0 + ks * 32 + g * 8);
        oacc[df] = MFMA16(pa[ks], vf, oacc[df]);
      }
    }
  }
  // finalize: divide by row sums, store attention output transposed [n][hid] bf16
#pragma unroll
  for (int reg = 0; reg < 4; ++reg) {
    float s = rsum[reg];
#pragma unroll
    for (int m = 1; m < 16; m <<= 1) s += __shfl_xor(s, m);
    rsum[reg] = 1.0f / s;
  }
#pragma unroll
  for (int df = 0; df < 4; ++df)
#pragma unroll
    for (int reg = 0; reg < 4; ++reg) {
      int i = i0 + g * 4 + reg;
      int d = df * 16 + r;
      float vo = oacc[df][reg] * rsum[reg];
      aot[((size_t)b << 18) + (size_t)i * 256 + h * 64 + d] = f2bf(vo);
    }
}

// ---------------- kernel 3: output projection + bias
// flat grid 512 = 16 o-tiles x 2 n-halves x 16 b, XCD-swizzled (q=64).
// 512 thr = 8 waves; wave: 16o x 64n.
__global__ __launch_bounds__(512, 6) void k_out(const ushort* __restrict__ woutb,
    const ushort* __restrict__ aot, const float* __restrict__ bout,
    float* __restrict__ out) {
  int bid = blockIdx.x;
  int lid = (bid & 7) * 64 + (bid >> 3);
  int ox = lid & 15;
  int t = lid >> 4;
  int nb = t & 1;
  int b = t >> 1;
  int o0 = ox * 16;
  int tid = threadIdx.x, l = tid & 63, w = tid >> 6, r = l & 15, g = l >> 4;
  const ushort* Ab = woutb + (size_t)(o0 + r) * 256 + g * 8;
  const ushort* Bb = aot + ((size_t)b << 18) + (size_t)(nb * 512 + w * 64 + r) * 256 + g * 8;
  f32x4 acc[4];
#pragma unroll
  for (int j = 0; j < 4; ++j) acc[j] = (f32x4){0.f, 0.f, 0.f, 0.f};
#pragma unroll
  for (int ks = 0; ks < 8; ++ks) {
    short8 a0 = ld8(Ab + ks * 32);
#pragma unroll
    for (int nf = 0; nf < 4; ++nf) {
      short8 bv = ld8(Bb + (size_t)nf * 4096 + ks * 32);
      acc[nf] = MFMA16(a0, bv, acc[nf]);
    }
  }
  float bias[4];
#pragma unroll
  for (int reg = 0; reg < 4; ++reg) bias[reg] = bout[o0 + g * 4 + reg];
#pragma unroll
  for (int nf = 0; nf < 4; ++nf)
#pragma unroll
    for (int reg = 0; reg < 4; ++reg) {
      size_t o = (size_t)(b * 256 + o0 + g * 4 + reg);
      out[(o << 10) + nb * 512 + w * 64 + nf * 16 + r] = acc[nf][reg] + bias[reg];
    }
}

extern "C" void kernel_launch(void* const* d_in, const int* in_sizes, int n_in,
                              void* d_out, int out_size, void* d_ws, size_t ws_size,
                              hipStream_t stream) {
  const float* x     = (const float*)d_in[0];
  const float* y     = (const float*)d_in[1];
  const float* wqkv  = (const float*)d_in[2];
  const float* wout  = (const float*)d_in[3];
  const float* bout  = (const float*)d_in[4];
  float* out = (float*)d_out;
  char* ws = (char*)d_ws;

  // Aliased workspace (~40.6 MB). Lifetimes:
  //  A: xbt (dead after k_qkv)  -> qt  (written by k_normt)
  //  B: ybt (dead after k_qkv)  -> kt  (written by k_normt)
  //  C: qraw (dead after k_normt) -> aot (written by k_attn)
  ushort* xbt   = (ushort*)(ws + 0ull);          // 8 MiB
  ushort* qt    = (ushort*)(ws + 0ull);
  ushort* ybt   = (ushort*)(ws + 8388608ull);    // 8 MiB
  ushort* kt    = (ushort*)(ws + 8388608ull);
  ushort* qraw  = (ushort*)(ws + 16777216ull);   // 8 MiB
  ushort* aot   = (ushort*)(ws + 16777216ull);
  ushort* kraw  = (ushort*)(ws + 25165824ull);   // 8 MiB
  ushort* vbuf  = (ushort*)(ws + 33554432ull);   // 8 MiB
  ushort* wqkvb = (ushort*)(ws + 41943040ull);   // 384 KiB
  ushort* woutb = (ushort*)(ws + 42336256ull);   // 128 KiB
  float*  norms2= (float*) (ws + 42467328ull);   // 64 KiB (2 partial slices)

  k_tcvt<<<2048, 256, 0, stream>>>(x, y, xbt, ybt);
  k_wcvt<<<256, 256, 0, stream>>>(wqkv, wout, wqkvb, woutb);
  k_qkv<<<768, 512, 0, stream>>>(wqkvb, xbt, ybt, qraw, kraw, vbuf, norms2);
  k_normt<<<2048, 256, 0, stream>>>(qraw, kraw, norms2, qt, kt);
  k_attn<<<1024, 256, 0, stream>>>(qt, kt, vbuf, aot);
  k_out<<<512, 512, 0, stream>>>(woutb, aot, bout, out);
}

// Round 4
// 186.769 us; speedup vs baseline: 1.4615x; 1.4615x over previous
//
#include <hip/hip_runtime.h>
#include <hip/hip_bf16.h>
#include <stdint.h>

typedef __attribute__((ext_vector_type(8))) short short8;
typedef __attribute__((ext_vector_type(4))) float f32x4;

#define MFMA16(a, b, c) __builtin_amdgcn_mfma_f32_16x16x32_bf16((a), (b), (c), 0, 0, 0)

// sizes: B=16, C=256, N=1024 (32x32), HEADS=4, DHEAD=64, HID=256, OTOT=768

__device__ __forceinline__ ushort f2bf(float f) {
  union { float f; unsigned u; } x; x.f = f;
  unsigned r = x.u + 0x7FFFu + ((x.u >> 16) & 1u);
  return (ushort)(r >> 16);
}

__device__ __forceinline__ float bf2f(ushort u) {
  union { unsigned u; float f; } x; x.u = ((unsigned)u) << 16;
  return x.f;
}

__device__ __forceinline__ short8 ld8(const ushort* p) {
  return *reinterpret_cast<const short8*>(p);
}

// async global->LDS, 16B per lane; LDS dest = wave-uniform base + lane*16 (m104);
// global src is per-lane (m173). CK-style addrspace incantation.
__device__ __forceinline__ void gll16(const void* g, void* l) {
  __builtin_amdgcn_global_load_lds(
      reinterpret_cast<const __attribute__((address_space(1))) unsigned int*>(
          reinterpret_cast<uintptr_t>(g)),
      reinterpret_cast<__attribute__((address_space(3))) unsigned int*>(
          reinterpret_cast<uintptr_t>(l)),
      16, 0, 0);
}

// ---------------- kernel 0a: transpose + convert x,y (b,c,n)f32 -> (b,n,c)bf16
__global__ __launch_bounds__(256) void k_tcvt(const float* __restrict__ x,
    const float* __restrict__ y, ushort* __restrict__ xbt, ushort* __restrict__ ybt) {
  int tile = blockIdx.x;
  const float* src; ushort* dst;
  if (tile >= 1024) { tile -= 1024; src = y; dst = ybt; }
  else { src = x; dst = xbt; }
  int b = tile >> 6;
  int c0 = ((tile >> 4) & 3) << 6;
  int n0 = (tile & 15) << 6;
  __shared__ ushort lds[64][65];
  int tid = threadIdx.x;
  int nl = tid & 63, cl = tid >> 6;
  const float* sb = src + ((size_t)b << 18);
#pragma unroll
  for (int s = 0; s < 16; ++s) {
    int c = cl + (s << 2);
    lds[c][nl] = f2bf(sb[(size_t)(c0 + c) * 1024 + n0 + nl]);
  }
  __syncthreads();
  ushort* db = dst + ((size_t)b << 18);
  int cl2 = tid & 63, nl2 = tid >> 6;
#pragma unroll
  for (int s = 0; s < 16; ++s) {
    int n = nl2 + (s << 2);
    db[(size_t)(n0 + n) * 256 + c0 + cl2] = lds[cl2][n];
  }
}

// ---------------- kernel 0b: convert weights to bf16 (same layout, [o][c])
__global__ __launch_bounds__(256) void k_wcvt(const float* __restrict__ wqkv,
    const float* __restrict__ wout, ushort* __restrict__ wqkvb, ushort* __restrict__ woutb) {
  const int total1 = 768 * 256;
  const int total = total1 + 256 * 256;
  for (int i = blockIdx.x * 256 + threadIdx.x; i < total; i += gridDim.x * 256) {
    if (i < total1) wqkvb[i] = f2bf(wqkv[i]);
    else woutb[i - total1] = f2bf(wout[i - total1]);
  }
}

// ---------------- kernel 1: QKV projection GEMM + partial row sum-of-squares
// flat grid 768 = 24 o-tiles x 2 n-halves x 16 b, XCD-swizzled (q=96).
// 512 thr = 8 waves; wave: 32o x 64n.
__global__ __launch_bounds__(512, 6) void k_qkv(const ushort* __restrict__ wqkvb,
    const ushort* __restrict__ xbt, const ushort* __restrict__ ybt,
    ushort* __restrict__ qraw, ushort* __restrict__ kraw,
    ushort* __restrict__ vbuf, float* __restrict__ norms2) {
  int bid = blockIdx.x;
  int lid = (bid & 7) * 96 + (bid >> 3);   // XCD swizzle: 2 b-panels per XCD
  int ox = lid % 24;
  int t = lid / 24;
  int nb = t & 1;
  int b = t >> 1;
  int o0 = ox * 32;
  const ushort* Bsrc = (o0 < 256) ? xbt : ybt;   // q from x; k,v from y
  const ushort* Bm = Bsrc + ((size_t)b << 18);
  int tid = threadIdx.x;
  int l = tid & 63, w = tid >> 6;
  int r = l & 15, g = l >> 4;
  const ushort* Ab = wqkvb + (size_t)(o0 + r) * 256 + g * 8;
  const ushort* Bb = Bm + (size_t)(nb * 512 + w * 64 + r) * 256 + g * 8;
  f32x4 acc[2][4];
#pragma unroll
  for (int i = 0; i < 2; ++i)
#pragma unroll
    for (int j = 0; j < 4; ++j) acc[i][j] = (f32x4){0.f, 0.f, 0.f, 0.f};
#pragma unroll
  for (int ks = 0; ks < 8; ++ks) {
    short8 a0 = ld8(Ab + ks * 32);
    short8 a1 = ld8(Ab + 4096 + ks * 32);
#pragma unroll
    for (int nf = 0; nf < 4; ++nf) {
      short8 bv = ld8(Bb + (size_t)nf * 4096 + ks * 32);
      acc[0][nf] = MFMA16(a0, bv, acc[0][nf]);
      acc[1][nf] = MFMA16(a1, bv, acc[1][nf]);
    }
  }
  // partial row sum-of-squares for q,k over this block's 512 n
  __shared__ float snorm[8][32];
  if (o0 < 512) {
    float ss[2][4];
#pragma unroll
    for (int mf = 0; mf < 2; ++mf)
#pragma unroll
      for (int reg = 0; reg < 4; ++reg) {
        float s = 0.f;
#pragma unroll
        for (int nf = 0; nf < 4; ++nf) { float v = acc[mf][nf][reg]; s += v * v; }
#pragma unroll
        for (int m = 1; m < 16; m <<= 1) s += __shfl_xor(s, m);
        ss[mf][reg] = s;
      }
    if (r == 0) {
#pragma unroll
      for (int mf = 0; mf < 2; ++mf)
#pragma unroll
        for (int reg = 0; reg < 4; ++reg)
          snorm[w][mf * 16 + g * 4 + reg] = ss[mf][reg];
    }
    __syncthreads();
    if (tid < 32) {
      float s = 0.f;
#pragma unroll
      for (int w2 = 0; w2 < 8; ++w2) s += snorm[w2][tid];
      norms2[(nb * 16 + b) * 512 + o0 + tid] = s;
    }
  }
  // store raw q,k and v as bf16, [b][256][1024] each
#pragma unroll
  for (int mf = 0; mf < 2; ++mf) {
    int ob = o0 + mf * 16 + g * 4;
#pragma unroll
    for (int nf = 0; nf < 4; ++nf) {
      int n = nb * 512 + w * 64 + nf * 16 + r;
#pragma unroll
      for (int reg = 0; reg < 4; ++reg) {
        ushort v = f2bf(acc[mf][nf][reg]);
        int oo = ob + reg;
        if (o0 < 256)       qraw[(((size_t)b * 256 + oo) << 10) + n] = v;
        else if (o0 < 512)  kraw[(((size_t)b * 256 + (oo - 256)) << 10) + n] = v;
        else                vbuf[(((size_t)b * 256 + (oo - 512)) << 10) + n] = v;
      }
    }
  }
}

// ---------------- kernel 1b: scale by 1/norm (SCALE folded into q) + transpose to [n][d] bf16
__global__ __launch_bounds__(256) void k_normt(const ushort* __restrict__ qraw,
    const ushort* __restrict__ kraw, const float* __restrict__ norms2,
    ushort* __restrict__ qt, ushort* __restrict__ kt) {
  int tile = blockIdx.x;
  const ushort* src; ushort* dst; int which;
  if (tile >= 1024) { tile -= 1024; src = kraw; dst = kt; which = 1; }
  else { src = qraw; dst = qt; which = 0; }
  int b = tile >> 6;
  int h = (tile >> 4) & 3;
  int n0 = (tile & 15) << 6;
  __shared__ ushort lds[64][65];
  __shared__ float fs[64];
  int tid = threadIdx.x;
  if (tid < 64) {
    int idx = b * 512 + which * 256 + h * 64 + tid;
    float ss = norms2[idx] + norms2[8192 + idx];
    fs[tid] = (which ? 1.0f : 10.0f) / fmaxf(sqrtf(ss), 1e-12f);
  }
  __syncthreads();
  const ushort* sb = src + (((size_t)b * 256 + h * 64) << 10);
  int nl = tid & 63, dl = tid >> 6;
#pragma unroll
  for (int s = 0; s < 16; ++s) {
    int d = dl + (s << 2);
    lds[d][nl] = f2bf(bf2f(sb[((size_t)d << 10) + n0 + nl]) * fs[d]);
  }
  __syncthreads();
  ushort* db = dst + (((size_t)(b * 4 + h) << 10) + n0) * 64;
  int dl2 = tid & 63, nl2 = tid >> 6;
#pragma unroll
  for (int s = 0; s < 16; ++s) {
    int n = nl2 + (s << 2);
    db[(size_t)n * 64 + dl2] = lds[dl2][n];
  }
}

// ---------------- kernel 2: fused attention, LDS-staged K/V (double-buffered),
// no-max softmax, unnormalized accumulate.
// grid dim3(64 hb, 4 it): bid%8 = hb%8 -> all i-tiles of 8 hb share one XCD
// (2 MB K/V working set, L2-resident). 512 thr = 8 waves; wave owns 32 q-rows.
__global__ __launch_bounds__(512, 2) void k_attn(const ushort* __restrict__ qt,
    const ushort* __restrict__ kt, const ushort* __restrict__ vbuf,
    ushort* __restrict__ aot) {
  int hb = blockIdx.x;            // b*4 + h
  int it = blockIdx.y;            // 0..3
  int h = hb & 3, b = hb >> 2;
  int tid = threadIdx.x;
  int l = tid & 63, w = tid >> 6;
  int r = l & 15, g = l >> 4;
  size_t ho = ((size_t)hb) << 16;
  const ushort* Q = qt + ho;      // [n][64]
  const char* Kg = (const char*)(kt + ho);                                  // [n][64]
  const char* Vg = (const char*)(vbuf + ((size_t)b << 18) + ((size_t)h << 16));  // [d][n]
  int i0 = it * 256 + w * 32;

  __shared__ __align__(16) ushort Kb[2][4096];   // 64 rows x 64 cols, XOR-swizzled
  __shared__ __align__(16) ushort Vb[2][4096];
  __shared__ __align__(16) ushort plds[8][2048]; // per-wave 32x64 P, XOR-swizzled

  // staging geometry: tile = 8 KB; wave w moves bytes [w*1024, w*1024+1024)
  int L = w * 1024 + l * 16;            // linear LDS byte offset in tile
  int srow = L >> 7;                    // tile row (64 x 128B rows)
  int swz = (srow & 7) << 4;
  int ksrc = L ^ swz;                   // K: contiguous tile, involutive swizzle
  int vsrc_col = (L & 127) ^ swz;       // V: per-row 128B slice of [d][1024]

  // Q fragments (one-time gather from global)
  short8 qa[2][2];
#pragma unroll
  for (int mf = 0; mf < 2; ++mf)
#pragma unroll
    for (int ks = 0; ks < 2; ++ks)
      qa[mf][ks] = ld8(Q + (size_t)(i0 + mf * 16 + r) * 64 + ks * 32 + g * 8);

  f32x4 oacc[2][4];
  float rsum[2][4];
#pragma unroll
  for (int mf = 0; mf < 2; ++mf)
#pragma unroll
    for (int j = 0; j < 4; ++j) { oacc[mf][j] = (f32x4){0.f, 0.f, 0.f, 0.f}; rsum[mf][j] = 0.f; }

#define STAGE(buf, j0v) do { \
    gll16(Kg + (j0v) * 128 + ksrc, (char*)&Kb[buf][0] + w * 1024); \
    gll16(Vg + (size_t)srow * 2048 + (j0v) * 2 + vsrc_col, (char*)&Vb[buf][0] + w * 1024); \
  } while (0)

  STAGE(0, 0);
  __syncthreads();   // drains vmcnt before reads (G7)

  char* plc = (char*)plds[w];
  for (int t = 0; t < 16; ++t) {
    int cur = t & 1;
    if (t < 15) STAGE(cur ^ 1, (t + 1) * 64);
    const char* Kc = (const char*)&Kb[cur][0];
    const char* Vc = (const char*)&Vb[cur][0];
    // ---- QK^T on this 64-col tile
    f32x4 sacc[2][4];
#pragma unroll
    for (int mf = 0; mf < 2; ++mf)
#pragma unroll
      for (int nf = 0; nf < 4; ++nf) sacc[mf][nf] = (f32x4){0.f, 0.f, 0.f, 0.f};
#pragma unroll
    for (int nf = 0; nf < 4; ++nf) {
      int row = nf * 16 + r;
      int sw = (row & 7) << 4;
      short8 k0 = *reinterpret_cast<const short8*>(Kc + ((row * 128 + g * 16) ^ sw));
      short8 k1 = *reinterpret_cast<const short8*>(Kc + ((row * 128 + 64 + g * 16) ^ sw));
      sacc[0][nf] = MFMA16(qa[0][0], k0, sacc[0][nf]);
      sacc[0][nf] = MFMA16(qa[0][1], k1, sacc[0][nf]);
      sacc[1][nf] = MFMA16(qa[1][0], k0, sacc[1][nf]);
      sacc[1][nf] = MFMA16(qa[1][1], k1, sacc[1][nf]);
    }
    // ---- P = exp(S); row sums; P -> per-wave LDS (swizzled; bf16 truncation:
    // bias is common-mode between numerator and row-sum denominator)
#pragma unroll
    for (int mf = 0; mf < 2; ++mf)
#pragma unroll
      for (int nf = 0; nf < 4; ++nf)
#pragma unroll
        for (int reg = 0; reg < 4; ++reg) {
          float p = __expf(sacc[mf][nf][reg]);
          rsum[mf][reg] += p;
          union { float f; unsigned u; } cv; cv.f = p;
          int row = mf * 16 + g * 4 + reg;
          int xorv = ((row ^ (row >> 3)) & 7) << 4;
          int byteo = row * 128 + (((nf * 16 + r) * 2) ^ xorv);
          *(ushort*)(plc + byteo) = (ushort)(cv.u >> 16);
        }
    // read back as A-fragments
    short8 pa[2][2];
#pragma unroll
    for (int mf = 0; mf < 2; ++mf)
#pragma unroll
      for (int ks = 0; ks < 2; ++ks) {
        int row = mf * 16 + r;
        int xorv = (row ^ (row >> 3)) & 7;
        int blk = (ks * 4 + g) ^ xorv;
        pa[mf][ks] = *reinterpret_cast<const short8*>(plc + row * 128 + blk * 16);
      }
    // ---- O += P * V^T
#pragma unroll
    for (int df = 0; df < 4; ++df) {
      int row = df * 16 + r;
      int sw = (row & 7) << 4;
#pragma unroll
      for (int ks = 0; ks < 2; ++ks) {
        short8 vf = *reinterpret_cast<const short8*>(Vc + ((row * 128 + ks * 64 + g * 16) ^ sw));
        oacc[0][df] = MFMA16(pa[0][ks], vf, oacc[0][df]);
        oacc[1][df] = MFMA16(pa[1][ks], vf, oacc[1][df]);
      }
    }
    __syncthreads();  // next tile staged (vmcnt drained) + buf reuse safe
  }
#undef STAGE

  // finalize: divide by row sums, store attention output transposed [n][hid] bf16
#pragma unroll
  for (int mf = 0; mf < 2; ++mf)
#pragma unroll
    for (int reg = 0; reg < 4; ++reg) {
      float s = rsum[mf][reg];
#pragma unroll
      for (int m = 1; m < 16; m <<= 1) s += __shfl_xor(s, m);
      rsum[mf][reg] = 1.0f / s;
    }
#pragma unroll
  for (int mf = 0; mf < 2; ++mf)
#pragma unroll
    for (int df = 0; df < 4; ++df)
#pragma unroll
      for (int reg = 0; reg < 4; ++reg) {
        int i = i0 + mf * 16 + g * 4 + reg;
        int d = df * 16 + r;
        float vo = oacc[mf][df][reg] * rsum[mf][reg];
        aot[((size_t)b << 18) + (size_t)i * 256 + h * 64 + d] = f2bf(vo);
      }
}

// ---------------- kernel 3: output projection + bias
// flat grid 512 = 16 o-tiles x 2 n-halves x 16 b, XCD-swizzled (q=64).
// 512 thr = 8 waves; wave: 16o x 64n.
__global__ __launch_bounds__(512, 6) void k_out(const ushort* __restrict__ woutb,
    const ushort* __restrict__ aot, const float* __restrict__ bout,
    float* __restrict__ out) {
  int bid = blockIdx.x;
  int lid = (bid & 7) * 64 + (bid >> 3);
  int ox = lid & 15;
  int t = lid >> 4;
  int nb = t & 1;
  int b = t >> 1;
  int o0 = ox * 16;
  int tid = threadIdx.x, l = tid & 63, w = tid >> 6, r = l & 15, g = l >> 4;
  const ushort* Ab = woutb + (size_t)(o0 + r) * 256 + g * 8;
  const ushort* Bb = aot + ((size_t)b << 18) + (size_t)(nb * 512 + w * 64 + r) * 256 + g * 8;
  f32x4 acc[4];
#pragma unroll
  for (int j = 0; j < 4; ++j) acc[j] = (f32x4){0.f, 0.f, 0.f, 0.f};
#pragma unroll
  for (int ks = 0; ks < 8; ++ks) {
    short8 a0 = ld8(Ab + ks * 32);
#pragma unroll
    for (int nf = 0; nf < 4; ++nf) {
      short8 bv = ld8(Bb + (size_t)nf * 4096 + ks * 32);
      acc[nf] = MFMA16(a0, bv, acc[nf]);
    }
  }
  float bias[4];
#pragma unroll
  for (int reg = 0; reg < 4; ++reg) bias[reg] = bout[o0 + g * 4 + reg];
#pragma unroll
  for (int nf = 0; nf < 4; ++nf)
#pragma unroll
    for (int reg = 0; reg < 4; ++reg) {
      size_t o = (size_t)(b * 256 + o0 + g * 4 + reg);
      out[(o << 10) + nb * 512 + w * 64 + nf * 16 + r] = acc[nf][reg] + bias[reg];
    }
}

extern "C" void kernel_launch(void* const* d_in, const int* in_sizes, int n_in,
                              void* d_out, int out_size, void* d_ws, size_t ws_size,
                              hipStream_t stream) {
  const float* x     = (const float*)d_in[0];
  const float* y     = (const float*)d_in[1];
  const float* wqkv  = (const float*)d_in[2];
  const float* wout  = (const float*)d_in[3];
  const float* bout  = (const float*)d_in[4];
  float* out = (float*)d_out;
  char* ws = (char*)d_ws;

  // Aliased workspace (~40.6 MB). Lifetimes:
  //  A: xbt (dead after k_qkv)  -> qt  (written by k_normt)
  //  B: ybt (dead after k_qkv)  -> kt  (written by k_normt)
  //  C: qraw (dead after k_normt) -> aot (written by k_attn)
  ushort* xbt   = (ushort*)(ws + 0ull);          // 8 MiB
  ushort* qt    = (ushort*)(ws + 0ull);
  ushort* ybt   = (ushort*)(ws + 8388608ull);    // 8 MiB
  ushort* kt    = (ushort*)(ws + 8388608ull);
  ushort* qraw  = (ushort*)(ws + 16777216ull);   // 8 MiB
  ushort* aot   = (ushort*)(ws + 16777216ull);
  ushort* kraw  = (ushort*)(ws + 25165824ull);   // 8 MiB
  ushort* vbuf  = (ushort*)(ws + 33554432ull);   // 8 MiB
  ushort* wqkvb = (ushort*)(ws + 41943040ull);   // 384 KiB
  ushort* woutb = (ushort*)(ws + 42336256ull);   // 128 KiB
  float*  norms2= (float*) (ws + 42467328ull);   // 64 KiB (2 partial slices)

  k_tcvt<<<2048, 256, 0, stream>>>(x, y, xbt, ybt);
  k_wcvt<<<256, 256, 0, stream>>>(wqkv, wout, wqkvb, woutb);
  k_qkv<<<768, 512, 0, stream>>>(wqkvb, xbt, ybt, qraw, kraw, vbuf, norms2);
  k_normt<<<2048, 256, 0, stream>>>(qraw, kraw, norms2, qt, kt);
  k_attn<<<dim3(64, 4), 512, 0, stream>>>(qt, kt, vbuf, aot);
  k_out<<<512, 512, 0, stream>>>(woutb, aot, bout, out);
}

// Round 5
// 186.272 us; speedup vs baseline: 1.4654x; 1.0027x over previous
//
#include <hip/hip_runtime.h>
#include <hip/hip_bf16.h>
#include <stdint.h>

typedef __attribute__((ext_vector_type(8))) short short8;
typedef __attribute__((ext_vector_type(4))) float f32x4;
typedef __attribute__((ext_vector_type(4))) unsigned short ushort4v;

#define MFMA16(a, b, c) __builtin_amdgcn_mfma_f32_16x16x32_bf16((a), (b), (c), 0, 0, 0)

// sizes: B=16, C=256, N=1024 (32x32), HEADS=4, DHEAD=64, HID=256, OTOT=768

__device__ __forceinline__ ushort f2bf(float f) {
  union { float f; unsigned u; } x; x.f = f;
  unsigned r = x.u + 0x7FFFu + ((x.u >> 16) & 1u);
  return (ushort)(r >> 16);
}

__device__ __forceinline__ short8 ld8(const ushort* p) {
  return *reinterpret_cast<const short8*>(p);
}

// async global->LDS, 16B per lane; LDS dest = wave-uniform base + lane*16 (m104);
// global src is per-lane (m173).
__device__ __forceinline__ void gll16(const void* g, void* l) {
  __builtin_amdgcn_global_load_lds(
      reinterpret_cast<const __attribute__((address_space(1))) unsigned int*>(
          reinterpret_cast<uintptr_t>(g)),
      reinterpret_cast<__attribute__((address_space(3))) unsigned int*>(
          reinterpret_cast<uintptr_t>(l)),
      16, 0, 0);
}

// ---------------- kernel 0: transpose+convert x,y (b,c,n)f32 -> (b,n,c)bf16,
// plus weight conversion in the tail blocks (tile >= 2048).
__global__ __launch_bounds__(256) void k_tcvt(const float* __restrict__ x,
    const float* __restrict__ y, ushort* __restrict__ xbt, ushort* __restrict__ ybt,
    const float* __restrict__ wqkv, const float* __restrict__ wout,
    ushort* __restrict__ wqkvb, ushort* __restrict__ woutb) {
  int tile = blockIdx.x;
  if (tile >= 2048) {   // weight-conversion blocks (64 of them)
    const int total1 = 768 * 256;
    const int total = total1 + 256 * 256;
    for (int i = (tile - 2048) * 256 + threadIdx.x; i < total; i += 64 * 256) {
      if (i < total1) wqkvb[i] = f2bf(wqkv[i]);
      else woutb[i - total1] = f2bf(wout[i - total1]);
    }
    return;
  }
  const float* src; ushort* dst;
  if (tile >= 1024) { tile -= 1024; src = y; dst = ybt; }
  else { src = x; dst = xbt; }
  int b = tile >> 6;
  int c0 = ((tile >> 4) & 3) << 6;
  int n0 = (tile & 15) << 6;
  __shared__ ushort lds[64][65];
  int tid = threadIdx.x;
  int nl = tid & 63, cl = tid >> 6;
  const float* sb = src + ((size_t)b << 18);
#pragma unroll
  for (int s = 0; s < 16; ++s) {
    int c = cl + (s << 2);
    lds[c][nl] = f2bf(sb[(size_t)(c0 + c) * 1024 + n0 + nl]);
  }
  __syncthreads();
  ushort* db = dst + ((size_t)b << 18);
  int cl2 = tid & 63, nl2 = tid >> 6;
#pragma unroll
  for (int s = 0; s < 16; ++s) {
    int n = nl2 + (s << 2);
    db[(size_t)(n0 + n) * 256 + c0 + cl2] = lds[cl2][n];
  }
}

// ---------------- kernel 1: QKV projection GEMM with FUSED l2norm + transpose.
// flat grid 384 = 24 o-tiles x 16 b, XCD-swizzled (48/XCD = 2 batches' panels).
// 512 thr = 8 waves; wave: 32o x 128n (full n=1024 in-block -> norms block-local).
// q,k: normalized (SCALE folded into q) and written as [hb][n][64] packed ushort4.
// v: written [b][256][1024] bf16.
__global__ __launch_bounds__(512, 4) void k_qkv(const ushort* __restrict__ wqkvb,
    const ushort* __restrict__ xbt, const ushort* __restrict__ ybt,
    ushort* __restrict__ qt, ushort* __restrict__ kt, ushort* __restrict__ vbuf) {
  int bid = blockIdx.x;
  int lid = (bid & 7) * 48 + (bid >> 3);
  int ox = lid % 24;
  int b = lid / 24;
  int o0 = ox * 32;
  const ushort* Bsrc = (o0 < 256) ? xbt : ybt;   // q from x; k,v from y
  const ushort* Bm = Bsrc + ((size_t)b << 18);
  int tid = threadIdx.x;
  int l = tid & 63, w = tid >> 6;
  int r = l & 15, g = l >> 4;
  const ushort* Ab = wqkvb + (size_t)(o0 + r) * 256 + g * 8;
  const ushort* Bb = Bm + (size_t)(w * 128 + r) * 256 + g * 8;
  f32x4 acc[2][8];
#pragma unroll
  for (int i = 0; i < 2; ++i)
#pragma unroll
    for (int j = 0; j < 8; ++j) acc[i][j] = (f32x4){0.f, 0.f, 0.f, 0.f};
#pragma unroll
  for (int ks = 0; ks < 8; ++ks) {
    short8 a0 = ld8(Ab + ks * 32);
    short8 a1 = ld8(Ab + 4096 + ks * 32);
#pragma unroll
    for (int nf = 0; nf < 8; ++nf) {
      short8 bv = ld8(Bb + (size_t)nf * 4096 + ks * 32);
      acc[0][nf] = MFMA16(a0, bv, acc[0][nf]);
      acc[1][nf] = MFMA16(a1, bv, acc[1][nf]);
    }
  }
  if (o0 < 512) {
    // ---- block-local row sum-of-squares (rows complete: full n in block)
    __shared__ float snorm[8][32];
    __shared__ float fs[32];
    float ss[2][4];
#pragma unroll
    for (int mf = 0; mf < 2; ++mf)
#pragma unroll
      for (int reg = 0; reg < 4; ++reg) {
        float s = 0.f;
#pragma unroll
        for (int nf = 0; nf < 8; ++nf) { float v = acc[mf][nf][reg]; s += v * v; }
#pragma unroll
        for (int m = 1; m < 16; m <<= 1) s += __shfl_xor(s, m);
        ss[mf][reg] = s;
      }
    if (r == 0) {
#pragma unroll
      for (int mf = 0; mf < 2; ++mf)
#pragma unroll
        for (int reg = 0; reg < 4; ++reg)
          snorm[w][mf * 16 + g * 4 + reg] = ss[mf][reg];
    }
    __syncthreads();
    if (tid < 32) {
      float s = 0.f;
#pragma unroll
      for (int w2 = 0; w2 < 8; ++w2) s += snorm[w2][tid];
      fs[tid] = ((o0 < 256) ? 10.0f : 1.0f) / fmaxf(sqrtf(s), 1e-12f);
    }
    __syncthreads();
    float fr[2][4];
#pragma unroll
    for (int mf = 0; mf < 2; ++mf)
#pragma unroll
      for (int reg = 0; reg < 4; ++reg) fr[mf][reg] = fs[mf * 16 + g * 4 + reg];
    // ---- normalize in-register, pack 4 consecutive d, store [hb][n][64]
    int od = (o0 < 256) ? o0 : o0 - 256;      // 0..255
    int hh = od >> 6, d0 = od & 63;           // d0 in {0,32}
    ushort* dst = ((o0 < 256) ? qt : kt) + (((size_t)(b * 4 + hh)) << 16);
#pragma unroll
    for (int mf = 0; mf < 2; ++mf)
#pragma unroll
      for (int nf = 0; nf < 8; ++nf) {
        int n = w * 128 + nf * 16 + r;
        ushort4v u;
#pragma unroll
        for (int reg = 0; reg < 4; ++reg) u[reg] = f2bf(acc[mf][nf][reg] * fr[mf][reg]);
        *reinterpret_cast<ushort4v*>(dst + (size_t)n * 64 + d0 + mf * 16 + g * 4) = u;
      }
  } else {
    // ---- v: store [b][256][1024] bf16 (16-lane-contiguous 32B segments)
#pragma unroll
    for (int mf = 0; mf < 2; ++mf) {
      int ob = o0 - 512 + mf * 16 + g * 4;
#pragma unroll
      for (int nf = 0; nf < 8; ++nf) {
        int n = w * 128 + nf * 16 + r;
#pragma unroll
        for (int reg = 0; reg < 4; ++reg)
          vbuf[(((size_t)b * 256 + ob + reg) << 10) + n] = f2bf(acc[mf][nf][reg]);
      }
    }
  }
}

// ---------------- kernel 2: fused attention, LDS-staged K/V (double-buffered),
// no-max softmax, unnormalized accumulate.
// grid dim3(64 hb, 8 it): bid%8 = hb%8 -> all i-tiles of 8 hb share an XCD
// (2 MB K/V, L2-resident). 512 thr = 8 waves; wave owns 16 q-rows.
// LDS 48 KB -> 2 blocks/CU (16 waves/CU).
__global__ __launch_bounds__(512, 4) void k_attn(const ushort* __restrict__ qt,
    const ushort* __restrict__ kt, const ushort* __restrict__ vbuf,
    ushort* __restrict__ aot) {
  int hb = blockIdx.x;            // b*4 + h
  int it = blockIdx.y;            // 0..7
  int h = hb & 3, b = hb >> 2;
  int tid = threadIdx.x;
  int l = tid & 63, w = tid >> 6;
  int r = l & 15, g = l >> 4;
  size_t ho = ((size_t)hb) << 16;
  const ushort* Q = qt + ho;      // [n][64]
  const char* Kg = (const char*)(kt + ho);                                       // [n][64]
  const char* Vg = (const char*)(vbuf + ((size_t)b << 18) + ((size_t)h << 16));  // [d][n]
  int i0 = it * 128 + w * 16;

  __shared__ __align__(16) ushort Kb[2][4096];   // 64 rows x 64 cols, XOR-swizzled
  __shared__ __align__(16) ushort Vb[2][4096];
  __shared__ __align__(16) ushort plds[8][1024]; // per-wave 16x64 P, XOR-swizzled

  // staging geometry: tile = 8 KB; wave w moves bytes [w*1024, w*1024+1024)
  int L = w * 1024 + l * 16;            // linear LDS byte offset in tile
  int srow = L >> 7;                    // tile row (64 x 128B rows)
  int swz = (srow & 7) << 4;
  int ksrc = L ^ swz;                   // K: contiguous tile, involutive swizzle
  int vsrc_col = (L & 127) ^ swz;       // V: per-row 128B slice of [d][1024]

  short8 qa[2];
#pragma unroll
  for (int ks = 0; ks < 2; ++ks)
    qa[ks] = ld8(Q + (size_t)(i0 + r) * 64 + ks * 32 + g * 8);

  f32x4 oacc[4];
  float rsum[4];
#pragma unroll
  for (int j = 0; j < 4; ++j) { oacc[j] = (f32x4){0.f, 0.f, 0.f, 0.f}; rsum[j] = 0.f; }

#define STAGE(buf, j0v) do { \
    gll16(Kg + (j0v) * 128 + ksrc, (char*)&Kb[buf][0] + w * 1024); \
    gll16(Vg + (size_t)srow * 2048 + (j0v) * 2 + vsrc_col, (char*)&Vb[buf][0] + w * 1024); \
  } while (0)

  STAGE(0, 0);
  __syncthreads();   // drains vmcnt before reads

  char* plc = (char*)plds[w];
  for (int t = 0; t < 16; ++t) {
    int cur = t & 1;
    if (t < 15) STAGE(cur ^ 1, (t + 1) * 64);
    const char* Kc = (const char*)&Kb[cur][0];
    const char* Vc = (const char*)&Vb[cur][0];
    // ---- QK^T on this 64-col tile
    f32x4 sacc[4];
#pragma unroll
    for (int nf = 0; nf < 4; ++nf) sacc[nf] = (f32x4){0.f, 0.f, 0.f, 0.f};
#pragma unroll
    for (int nf = 0; nf < 4; ++nf) {
      int row = nf * 16 + r;
      int sw = (row & 7) << 4;
      short8 k0 = *reinterpret_cast<const short8*>(Kc + ((row * 128 + g * 16) ^ sw));
      short8 k1 = *reinterpret_cast<const short8*>(Kc + ((row * 128 + 64 + g * 16) ^ sw));
      sacc[nf] = MFMA16(qa[0], k0, sacc[nf]);
      sacc[nf] = MFMA16(qa[1], k1, sacc[nf]);
    }
    // ---- P = exp(S); row sums; P -> per-wave LDS (swizzled; bf16 truncation:
    // bias is common-mode between numerator and row-sum denominator)
#pragma unroll
    for (int nf = 0; nf < 4; ++nf)
#pragma unroll
      for (int reg = 0; reg < 4; ++reg) {
        float p = __expf(sacc[nf][reg]);
        rsum[reg] += p;
        union { float f; unsigned u; } cv; cv.f = p;
        int row = g * 4 + reg;
        int xorv = ((row ^ (row >> 3)) & 7) << 4;
        int byteo = row * 128 + (((nf * 16 + r) * 2) ^ xorv);
        *(ushort*)(plc + byteo) = (ushort)(cv.u >> 16);
      }
    // read back as A-fragments
    short8 pa[2];
#pragma unroll
    for (int ks = 0; ks < 2; ++ks) {
      int xorv = (r ^ (r >> 3)) & 7;
      int blk = (ks * 4 + g) ^ xorv;
      pa[ks] = *reinterpret_cast<const short8*>(plc + r * 128 + blk * 16);
    }
    // ---- O += P * V^T
#pragma unroll
    for (int df = 0; df < 4; ++df) {
      int row = df * 16 + r;
      int sw = (row & 7) << 4;
#pragma unroll
      for (int ks = 0; ks < 2; ++ks) {
        short8 vf = *reinterpret_cast<const short8*>(Vc + ((row * 128 + ks * 64 + g * 16) ^ sw));
        oacc[df] = MFMA16(pa[ks], vf, oacc[df]);
      }
    }
    __syncthreads();  // next tile staged (vmcnt drained) + buf reuse safe
  }
#undef STAGE

  // finalize: divide by row sums, store [n][hid] bf16
#pragma unroll
  for (int reg = 0; reg < 4; ++reg) {
    float s = rsum[reg];
#pragma unroll
    for (int m = 1; m < 16; m <<= 1) s += __shfl_xor(s, m);
    rsum[reg] = 1.0f / s;
  }
#pragma unroll
  for (int df = 0; df < 4; ++df)
#pragma unroll
    for (int reg = 0; reg < 4; ++reg) {
      int i = i0 + g * 4 + reg;
      int d = df * 16 + r;
      float vo = oacc[df][reg] * rsum[reg];
      aot[((size_t)b << 18) + (size_t)i * 256 + h * 64 + d] = f2bf(vo);
    }
}

// ---------------- kernel 3: output projection + bias
// flat grid 512 = 16 o-tiles x 2 n-halves x 16 b, XCD-swizzled (q=64).
// 512 thr = 8 waves; wave: 16o x 64n.
__global__ __launch_bounds__(512, 6) void k_out(const ushort* __restrict__ woutb,
    const ushort* __restrict__ aot, const float* __restrict__ bout,
    float* __restrict__ out) {
  int bid = blockIdx.x;
  int lid = (bid & 7) * 64 + (bid >> 3);
  int ox = lid & 15;
  int t = lid >> 4;
  int nb = t & 1;
  int b = t >> 1;
  int o0 = ox * 16;
  int tid = threadIdx.x, l = tid & 63, w = tid >> 6, r = l & 15, g = l >> 4;
  const ushort* Ab = woutb + (size_t)(o0 + r) * 256 + g * 8;
  const ushort* Bb = aot + ((size_t)b << 18) + (size_t)(nb * 512 + w * 64 + r) * 256 + g * 8;
  f32x4 acc[4];
#pragma unroll
  for (int j = 0; j < 4; ++j) acc[j] = (f32x4){0.f, 0.f, 0.f, 0.f};
#pragma unroll
  for (int ks = 0; ks < 8; ++ks) {
    short8 a0 = ld8(Ab + ks * 32);
#pragma unroll
    for (int nf = 0; nf < 4; ++nf) {
      short8 bv = ld8(Bb + (size_t)nf * 4096 + ks * 32);
      acc[nf] = MFMA16(a0, bv, acc[nf]);
    }
  }
  float bias[4];
#pragma unroll
  for (int reg = 0; reg < 4; ++reg) bias[reg] = bout[o0 + g * 4 + reg];
#pragma unroll
  for (int nf = 0; nf < 4; ++nf)
#pragma unroll
    for (int reg = 0; reg < 4; ++reg) {
      size_t o = (size_t)(b * 256 + o0 + g * 4 + reg);
      out[(o << 10) + nb * 512 + w * 64 + nf * 16 + r] = acc[nf][reg] + bias[reg];
    }
}

extern "C" void kernel_launch(void* const* d_in, const int* in_sizes, int n_in,
                              void* d_out, int out_size, void* d_ws, size_t ws_size,
                              hipStream_t stream) {
  const float* x     = (const float*)d_in[0];
  const float* y     = (const float*)d_in[1];
  const float* wqkv  = (const float*)d_in[2];
  const float* wout  = (const float*)d_in[3];
  const float* bout  = (const float*)d_in[4];
  float* out = (float*)d_out;
  char* ws = (char*)d_ws;

  // Workspace (~40.6 MB). Aliases: xbt dead after k_qkv -> aot reuses it.
  ushort* xbt   = (ushort*)(ws + 0ull);          // 8 MiB
  ushort* aot   = (ushort*)(ws + 0ull);          //   (written by k_attn)
  ushort* ybt   = (ushort*)(ws + 8388608ull);    // 8 MiB
  ushort* qt    = (ushort*)(ws + 16777216ull);   // 8 MiB
  ushort* kt    = (ushort*)(ws + 25165824ull);   // 8 MiB
  ushort* vbuf  = (ushort*)(ws + 33554432ull);   // 8 MiB
  ushort* wqkvb = (ushort*)(ws + 41943040ull);   // 384 KiB
  ushort* woutb = (ushort*)(ws + 42336256ull);   // 128 KiB

  k_tcvt<<<2112, 256, 0, stream>>>(x, y, xbt, ybt, wqkv, wout, wqkvb, woutb);
  k_qkv<<<384, 512, 0, stream>>>(wqkvb, xbt, ybt, qt, kt, vbuf);
  k_attn<<<dim3(64, 8), 512, 0, stream>>>(qt, kt, vbuf, aot);
  k_out<<<512, 512, 0, stream>>>(woutb, aot, bout, out);
}

// Round 6
// 160.765 us; speedup vs baseline: 1.6979x; 1.1587x over previous
//
#include <hip/hip_runtime.h>
#include <hip/hip_bf16.h>
#include <stdint.h>

typedef __attribute__((ext_vector_type(8))) short short8;
typedef __attribute__((ext_vector_type(4))) float f32x4;
typedef __attribute__((ext_vector_type(4))) unsigned short ushort4v;

#define MFMA16(a, b, c) __builtin_amdgcn_mfma_f32_16x16x32_bf16((a), (b), (c), 0, 0, 0)

// sizes: B=16, C=256, N=1024 (32x32), HEADS=4, DHEAD=64, HID=256, OTOT=768

__device__ __forceinline__ ushort f2bf(float f) {
  union { float f; unsigned u; } x; x.f = f;
  unsigned r = x.u + 0x7FFFu + ((x.u >> 16) & 1u);
  return (ushort)(r >> 16);
}

__device__ __forceinline__ short8 ld8(const ushort* p) {
  return *reinterpret_cast<const short8*>(p);
}

// async global->LDS, 16B per lane; LDS dest = wave-uniform base + lane*16 (m104);
// global src is per-lane (m173).
__device__ __forceinline__ void gll16(const void* g, void* l) {
  __builtin_amdgcn_global_load_lds(
      reinterpret_cast<const __attribute__((address_space(1))) unsigned int*>(
          reinterpret_cast<uintptr_t>(g)),
      reinterpret_cast<__attribute__((address_space(3))) unsigned int*>(
          reinterpret_cast<uintptr_t>(l)),
      16, 0, 0);
}

// Stage one 64 KB tile (128 rows x 512 B) with involutive swizzle
// (col16slot ^= row&7) pre-applied to the GLOBAL source; LDS stays linear.
// goff/ldsw precomputed per-thread (see callers).
__device__ __forceinline__ void stage_tile(const char* gbase, char* ldsbase,
                                           int goff, int ldsw) {
#pragma unroll
  for (int c = 0; c < 8; ++c)
    gll16(gbase + c * 8192 + goff, ldsbase + c * 8192 + ldsw);
}

// ---------------- kernel 0: transpose+convert x,y (b,c,n)f32 -> (b,n,c)bf16,
// plus weight conversion in the tail blocks (tile >= 2048).
__global__ __launch_bounds__(256) void k_tcvt(const float* __restrict__ x,
    const float* __restrict__ y, ushort* __restrict__ xbt, ushort* __restrict__ ybt,
    const float* __restrict__ wqkv, const float* __restrict__ wout,
    ushort* __restrict__ wqkvb, ushort* __restrict__ woutb) {
  int tile = blockIdx.x;
  if (tile >= 2048) {   // weight-conversion blocks (64 of them)
    const int total1 = 768 * 256;
    const int total = total1 + 256 * 256;
    for (int i = (tile - 2048) * 256 + threadIdx.x; i < total; i += 64 * 256) {
      if (i < total1) wqkvb[i] = f2bf(wqkv[i]);
      else woutb[i - total1] = f2bf(wout[i - total1]);
    }
    return;
  }
  const float* src; ushort* dst;
  if (tile >= 1024) { tile -= 1024; src = y; dst = ybt; }
  else { src = x; dst = xbt; }
  int b = tile >> 6;
  int c0 = ((tile >> 4) & 3) << 6;
  int n0 = (tile & 15) << 6;
  __shared__ ushort lds[64][65];
  int tid = threadIdx.x;
  int nl = tid & 63, cl = tid >> 6;
  const float* sb = src + ((size_t)b << 18);
#pragma unroll
  for (int s = 0; s < 16; ++s) {
    int c = cl + (s << 2);
    lds[c][nl] = f2bf(sb[(size_t)(c0 + c) * 1024 + n0 + nl]);
  }
  __syncthreads();
  ushort* db = dst + ((size_t)b << 18);
  int cl2 = tid & 63, nl2 = tid >> 6;
#pragma unroll
  for (int s = 0; s < 16; ++s) {
    int n = nl2 + (s << 2);
    db[(size_t)(n0 + n) * 256 + c0 + cl2] = lds[cl2][n];
  }
}

// ---------------- kernel 1: QKV projection GEMM with fused l2norm + transpose.
// flat grid 384 = 24 o-tiles x 16 b, XCD-swizzled (48/XCD = 2 batches' panels,
// 2 MB L2-resident). 512 thr = 8 waves. Block: 32o x 1024n (norm block-local).
// B staged via global_load_lds in 128n x 256c (64 KB) double-buffered tiles;
// A (weights, 16 KB) preloaded to registers.
// q,k: normalized (SCALE folded into q), stored [hb][n][64] packed ushort4.
// v: stored [b][256][1024] bf16.
__global__ __launch_bounds__(512, 2) void k_qkv(const ushort* __restrict__ wqkvb,
    const ushort* __restrict__ xbt, const ushort* __restrict__ ybt,
    ushort* __restrict__ qt, ushort* __restrict__ kt, ushort* __restrict__ vbuf) {
  int bid = blockIdx.x;
  int lid = (bid & 7) * 48 + (bid >> 3);
  int ox = lid % 24;
  int b = lid / 24;
  int o0 = ox * 32;
  const ushort* Bsrc = (o0 < 256) ? xbt : ybt;   // q from x; k,v from y
  const char* Bm = (const char*)(Bsrc + ((size_t)b << 18));   // [1024][256] bf16
  int tid = threadIdx.x;
  int l = tid & 63, w = tid >> 6;
  int r = l & 15, g = l >> 4;

  __shared__ __align__(16) char Bt[2][65536];
  __shared__ float snorm[8][32];
  __shared__ float fs[32];

  // A preload: 2 mf x 8 ks fragments (each wave holds the full 32-row A-tile)
  const ushort* Ab = wqkvb + (size_t)(o0 + r) * 256 + g * 8;
  short8 areg[2][8];
#pragma unroll
  for (int ks = 0; ks < 8; ++ks) {
    areg[0][ks] = ld8(Ab + ks * 32);
    areg[1][ks] = ld8(Ab + 4096 + ks * 32);
  }

  // staging geometry: thread moves 16B at linear tile byte Lb (per 8KB call c)
  int Lb = tid * 16;
  int trow = Lb >> 9;                              // 0..15 within call chunk
  int goff = trow * 512 + ((Lb & 511) ^ ((trow & 7) << 4));
  int ldsw = w * 1024;                             // wave-uniform dest base

  f32x4 acc[2][8];
#pragma unroll
  for (int i = 0; i < 2; ++i)
#pragma unroll
    for (int j = 0; j < 8; ++j) acc[i][j] = (f32x4){0.f, 0.f, 0.f, 0.f};

  stage_tile(Bm, &Bt[0][0], goff, ldsw);
  __syncthreads();

  int rr = w * 16 + r;               // row this lane reads from each tile
  int sw = (r & 7) << 4;
  for (int nt = 0; nt < 8; ++nt) {
    int cur = nt & 1;
    if (nt < 7) stage_tile(Bm + (size_t)(nt + 1) * 65536, &Bt[cur ^ 1][0], goff, ldsw);
    const char* Bc = &Bt[cur][0];
#pragma unroll
    for (int ks = 0; ks < 8; ++ks) {
      short8 bv = *reinterpret_cast<const short8*>(Bc + rr * 512 + ((ks * 64 + g * 16) ^ sw));
      acc[0][nt] = MFMA16(areg[0][ks], bv, acc[0][nt]);
      acc[1][nt] = MFMA16(areg[1][ks], bv, acc[1][nt]);
    }
    __syncthreads();
  }

  if (o0 < 512) {
    // ---- block-local row sum-of-squares (rows complete: full n in block)
    float ss[2][4];
#pragma unroll
    for (int mf = 0; mf < 2; ++mf)
#pragma unroll
      for (int reg = 0; reg < 4; ++reg) {
        float s = 0.f;
#pragma unroll
        for (int nt = 0; nt < 8; ++nt) { float v = acc[mf][nt][reg]; s += v * v; }
#pragma unroll
        for (int m = 1; m < 16; m <<= 1) s += __shfl_xor(s, m);
        ss[mf][reg] = s;
      }
    if (r == 0) {
#pragma unroll
      for (int mf = 0; mf < 2; ++mf)
#pragma unroll
        for (int reg = 0; reg < 4; ++reg)
          snorm[w][mf * 16 + g * 4 + reg] = ss[mf][reg];
    }
    __syncthreads();
    if (tid < 32) {
      float s = 0.f;
#pragma unroll
      for (int w2 = 0; w2 < 8; ++w2) s += snorm[w2][tid];
      fs[tid] = ((o0 < 256) ? 10.0f : 1.0f) / fmaxf(sqrtf(s), 1e-12f);
    }
    __syncthreads();
    float fr[2][4];
#pragma unroll
    for (int mf = 0; mf < 2; ++mf)
#pragma unroll
      for (int reg = 0; reg < 4; ++reg) fr[mf][reg] = fs[mf * 16 + g * 4 + reg];
    // ---- normalize in-register, pack 4 consecutive d, store [hb][n][64]
    int od = (o0 < 256) ? o0 : o0 - 256;      // 0..255
    int hh = od >> 6, d0 = od & 63;           // d0 in {0,32}
    ushort* dst = ((o0 < 256) ? qt : kt) + (((size_t)(b * 4 + hh)) << 16);
#pragma unroll
    for (int mf = 0; mf < 2; ++mf)
#pragma unroll
      for (int nt = 0; nt < 8; ++nt) {
        int n = nt * 128 + w * 16 + r;
        ushort4v u;
#pragma unroll
        for (int reg = 0; reg < 4; ++reg) u[reg] = f2bf(acc[mf][nt][reg] * fr[mf][reg]);
        *reinterpret_cast<ushort4v*>(dst + (size_t)n * 64 + d0 + mf * 16 + g * 4) = u;
      }
  } else {
    // ---- v: store [b][256][1024] bf16 (16-lane-contiguous 32B segments)
#pragma unroll
    for (int mf = 0; mf < 2; ++mf) {
      int ob = o0 - 512 + mf * 16 + g * 4;
#pragma unroll
      for (int nt = 0; nt < 8; ++nt) {
        int n = nt * 128 + w * 16 + r;
#pragma unroll
        for (int reg = 0; reg < 4; ++reg)
          vbuf[(((size_t)b * 256 + ob + reg) << 10) + n] = f2bf(acc[mf][nt][reg]);
      }
    }
  }
}

// ---------------- kernel 2: fused attention, LDS-staged K/V (double-buffered),
// no-max softmax, unnormalized accumulate.
// grid dim3(64 hb, 8 it): bid%8 = hb%8 -> all i-tiles of 8 hb share an XCD
// (2 MB K/V, L2-resident). 512 thr = 8 waves; wave owns 16 q-rows.
// LDS 48 KB -> 2 blocks/CU (16 waves/CU).
__global__ __launch_bounds__(512, 4) void k_attn(const ushort* __restrict__ qt,
    const ushort* __restrict__ kt, const ushort* __restrict__ vbuf,
    ushort* __restrict__ aot) {
  int hb = blockIdx.x;            // b*4 + h
  int it = blockIdx.y;            // 0..7
  int h = hb & 3, b = hb >> 2;
  int tid = threadIdx.x;
  int l = tid & 63, w = tid >> 6;
  int r = l & 15, g = l >> 4;
  size_t ho = ((size_t)hb) << 16;
  const ushort* Q = qt + ho;      // [n][64]
  const char* Kg = (const char*)(kt + ho);                                       // [n][64]
  const char* Vg = (const char*)(vbuf + ((size_t)b << 18) + ((size_t)h << 16));  // [d][n]
  int i0 = it * 128 + w * 16;

  __shared__ __align__(16) ushort Kb[2][4096];   // 64 rows x 64 cols, XOR-swizzled
  __shared__ __align__(16) ushort Vb[2][4096];
  __shared__ __align__(16) ushort plds[8][1024]; // per-wave 16x64 P, XOR-swizzled

  // staging geometry: tile = 8 KB; wave w moves bytes [w*1024, w*1024+1024)
  int L = w * 1024 + l * 16;            // linear LDS byte offset in tile
  int srow = L >> 7;                    // tile row (64 x 128B rows)
  int swz = (srow & 7) << 4;
  int ksrc = L ^ swz;                   // K: contiguous tile, involutive swizzle
  int vsrc_col = (L & 127) ^ swz;       // V: per-row 128B slice of [d][1024]

  short8 qa[2];
#pragma unroll
  for (int ks = 0; ks < 2; ++ks)
    qa[ks] = ld8(Q + (size_t)(i0 + r) * 64 + ks * 32 + g * 8);

  f32x4 oacc[4];
  float rsum[4];
#pragma unroll
  for (int j = 0; j < 4; ++j) { oacc[j] = (f32x4){0.f, 0.f, 0.f, 0.f}; rsum[j] = 0.f; }

#define STAGE(buf, j0v) do { \
    gll16(Kg + (j0v) * 128 + ksrc, (char*)&Kb[buf][0] + w * 1024); \
    gll16(Vg + (size_t)srow * 2048 + (j0v) * 2 + vsrc_col, (char*)&Vb[buf][0] + w * 1024); \
  } while (0)

  STAGE(0, 0);
  __syncthreads();   // drains vmcnt before reads

  char* plc = (char*)plds[w];
  for (int t = 0; t < 16; ++t) {
    int cur = t & 1;
    if (t < 15) STAGE(cur ^ 1, (t + 1) * 64);
    const char* Kc = (const char*)&Kb[cur][0];
    const char* Vc = (const char*)&Vb[cur][0];
    // ---- QK^T on this 64-col tile
    f32x4 sacc[4];
#pragma unroll
    for (int nf = 0; nf < 4; ++nf) sacc[nf] = (f32x4){0.f, 0.f, 0.f, 0.f};
#pragma unroll
    for (int nf = 0; nf < 4; ++nf) {
      int row = nf * 16 + r;
      int sw = (row & 7) << 4;
      short8 k0 = *reinterpret_cast<const short8*>(Kc + ((row * 128 + g * 16) ^ sw));
      short8 k1 = *reinterpret_cast<const short8*>(Kc + ((row * 128 + 64 + g * 16) ^ sw));
      sacc[nf] = MFMA16(qa[0], k0, sacc[nf]);
      sacc[nf] = MFMA16(qa[1], k1, sacc[nf]);
    }
    // ---- P = exp(S); row sums; P -> per-wave LDS (swizzled; bf16 truncation:
    // bias is common-mode between numerator and row-sum denominator)
#pragma unroll
    for (int nf = 0; nf < 4; ++nf)
#pragma unroll
      for (int reg = 0; reg < 4; ++reg) {
        float p = __expf(sacc[nf][reg]);
        rsum[reg] += p;
        union { float f; unsigned u; } cv; cv.f = p;
        int row = g * 4 + reg;
        int xorv = ((row ^ (row >> 3)) & 7) << 4;
        int byteo = row * 128 + (((nf * 16 + r) * 2) ^ xorv);
        *(ushort*)(plc + byteo) = (ushort)(cv.u >> 16);
      }
    // read back as A-fragments
    short8 pa[2];
#pragma unroll
    for (int ks = 0; ks < 2; ++ks) {
      int xorv = (r ^ (r >> 3)) & 7;
      int blk = (ks * 4 + g) ^ xorv;
      pa[ks] = *reinterpret_cast<const short8*>(plc + r * 128 + blk * 16);
    }
    // ---- O += P * V^T
#pragma unroll
    for (int df = 0; df < 4; ++df) {
      int row = df * 16 + r;
      int sw = (row & 7) << 4;
#pragma unroll
      for (int ks = 0; ks < 2; ++ks) {
        short8 vf = *reinterpret_cast<const short8*>(Vc + ((row * 128 + ks * 64 + g * 16) ^ sw));
        oacc[df] = MFMA16(pa[ks], vf, oacc[df]);
      }
    }
    __syncthreads();  // next tile staged (vmcnt drained) + buf reuse safe
  }
#undef STAGE

  // finalize: divide by row sums, store [n][hid] bf16
#pragma unroll
  for (int reg = 0; reg < 4; ++reg) {
    float s = rsum[reg];
#pragma unroll
    for (int m = 1; m < 16; m <<= 1) s += __shfl_xor(s, m);
    rsum[reg] = 1.0f / s;
  }
#pragma unroll
  for (int df = 0; df < 4; ++df)
#pragma unroll
    for (int reg = 0; reg < 4; ++reg) {
      int i = i0 + g * 4 + reg;
      int d = df * 16 + r;
      float vo = oacc[df][reg] * rsum[reg];
      aot[((size_t)b << 18) + (size_t)i * 256 + h * 64 + d] = f2bf(vo);
    }
}

// ---------------- kernel 3: output projection + bias, LDS-staged B.
// flat grid 256 = 8 o-tiles x 2 n-halves x 16 b, XCD-swizzled (32/XCD =
// 2 batches' aot panels, 1 MB L2-resident). 512 thr = 8 waves.
// Block: 32o x 512n; B staged in 4 x 64 KB double-buffered tiles; A preloaded.
__global__ __launch_bounds__(512, 2) void k_out(const ushort* __restrict__ woutb,
    const ushort* __restrict__ aot, const float* __restrict__ bout,
    float* __restrict__ out) {
  int bid = blockIdx.x;
  int lid = (bid & 7) * 32 + (bid >> 3);
  int ox = lid & 7;
  int t = lid >> 3;
  int nb = t & 1;
  int b = t >> 1;
  int o0 = ox * 32;
  int tid = threadIdx.x, l = tid & 63, w = tid >> 6, r = l & 15, g = l >> 4;
  const char* Bm = (const char*)(aot + ((size_t)b << 18) + ((size_t)nb << 17));  // [512][256] bf16

  __shared__ __align__(16) char Bt[2][65536];

  // A preload: woutb rows o0..o0+31
  const ushort* Ab = woutb + (size_t)(o0 + r) * 256 + g * 8;
  short8 areg[2][8];
#pragma unroll
  for (int ks = 0; ks < 8; ++ks) {
    areg[0][ks] = ld8(Ab + ks * 32);
    areg[1][ks] = ld8(Ab + 4096 + ks * 32);
  }

  int Lb = tid * 16;
  int trow = Lb >> 9;
  int goff = trow * 512 + ((Lb & 511) ^ ((trow & 7) << 4));
  int ldsw = w * 1024;

  f32x4 acc[2][4];
#pragma unroll
  for (int i = 0; i < 2; ++i)
#pragma unroll
    for (int j = 0; j < 4; ++j) acc[i][j] = (f32x4){0.f, 0.f, 0.f, 0.f};

  stage_tile(Bm, &Bt[0][0], goff, ldsw);
  __syncthreads();

  int rr = w * 16 + r;
  int sw = (r & 7) << 4;
  for (int nt = 0; nt < 4; ++nt) {
    int cur = nt & 1;
    if (nt < 3) stage_tile(Bm + (size_t)(nt + 1) * 65536, &Bt[cur ^ 1][0], goff, ldsw);
    const char* Bc = &Bt[cur][0];
#pragma unroll
    for (int ks = 0; ks < 8; ++ks) {
      short8 bv = *reinterpret_cast<const short8*>(Bc + rr * 512 + ((ks * 64 + g * 16) ^ sw));
      acc[0][nt] = MFMA16(areg[0][ks], bv, acc[0][nt]);
      acc[1][nt] = MFMA16(areg[1][ks], bv, acc[1][nt]);
    }
    __syncthreads();
  }

  float bias[2][4];
#pragma unroll
  for (int mf = 0; mf < 2; ++mf)
#pragma unroll
    for (int reg = 0; reg < 4; ++reg) bias[mf][reg] = bout[o0 + mf * 16 + g * 4 + reg];
#pragma unroll
  for (int mf = 0; mf < 2; ++mf)
#pragma unroll
    for (int nt = 0; nt < 4; ++nt)
#pragma unroll
      for (int reg = 0; reg < 4; ++reg) {
        size_t o = (size_t)(b * 256 + o0 + mf * 16 + g * 4 + reg);
        int n = nb * 512 + nt * 128 + w * 16 + r;
        out[(o << 10) + n] = acc[mf][nt][reg] + bias[mf][reg];
      }
}

extern "C" void kernel_launch(void* const* d_in, const int* in_sizes, int n_in,
                              void* d_out, int out_size, void* d_ws, size_t ws_size,
                              hipStream_t stream) {
  const float* x     = (const float*)d_in[0];
  const float* y     = (const float*)d_in[1];
  const float* wqkv  = (const float*)d_in[2];
  const float* wout  = (const float*)d_in[3];
  const float* bout  = (const float*)d_in[4];
  float* out = (float*)d_out;
  char* ws = (char*)d_ws;

  // Workspace (~40.6 MB). Aliases: xbt dead after k_qkv -> aot reuses it.
  ushort* xbt   = (ushort*)(ws + 0ull);          // 8 MiB
  ushort* aot   = (ushort*)(ws + 0ull);          //   (written by k_attn)
  ushort* ybt   = (ushort*)(ws + 8388608ull);    // 8 MiB
  ushort* qt    = (ushort*)(ws + 16777216ull);   // 8 MiB
  ushort* kt    = (ushort*)(ws + 25165824ull);   // 8 MiB
  ushort* vbuf  = (ushort*)(ws + 33554432ull);   // 8 MiB
  ushort* wqkvb = (ushort*)(ws + 41943040ull);   // 384 KiB
  ushort* woutb = (ushort*)(ws + 42336256ull);   // 128 KiB

  k_tcvt<<<2112, 256, 0, stream>>>(x, y, xbt, ybt, wqkv, wout, wqkvb, woutb);
  k_qkv<<<384, 512, 0, stream>>>(wqkvb, xbt, ybt, qt, kt, vbuf);
  k_attn<<<dim3(64, 8), 512, 0, stream>>>(qt, kt, vbuf, aot);
  k_out<<<256, 512, 0, stream>>>(woutb, aot, bout, out);
}